// Round 9
// baseline (226.913 us; speedup 1.0000x reference)
//
#include <hip/hip_runtime.h>

typedef unsigned short u16;
typedef __attribute__((ext_vector_type(8))) short short8;
typedef __attribute__((ext_vector_type(4))) float f32x4;
typedef __attribute__((ext_vector_type(4))) unsigned u32x4;

// Problem dims
#define Bq 4
#define Sq 2048
#define Dq 1024
#define Hq 16
#define HDq 64
#define BSq 8192   // B*S

// Q pre-scale: 1/sqrt(64) * log2(e)  (softmax done in exp2 domain)
#define QSCALE 0.18033688011112042f

__device__ __forceinline__ u16 f2bf(float f) {
  unsigned u = __builtin_bit_cast(unsigned, f);
  unsigned r = u + 0x7fffu + ((u >> 16) & 1u);
  return (u16)(r >> 16);
}

// pack two floats -> (bf16(a) | bf16(b)<<16)
__device__ __forceinline__ unsigned pk2(float a, float b) {
  unsigned ua = __builtin_bit_cast(unsigned, a) + 0x8000u;
  unsigned ub = __builtin_bit_cast(unsigned, b) + 0x8000u;
  return __builtin_amdgcn_perm(ub, ua, 0x07060302u);
}

// single-instruction pack: dst = {lo: bf16(a), hi: bf16(b)}
__device__ __forceinline__ unsigned cvtpk(float a, float b) {
  unsigned r;
  asm("v_cvt_pk_bf16_f32 %0, %1, %2" : "=v"(r) : "v"(a), "v"(b));
  return r;
}

// async global->LDS, 16B per lane (dest = wave-uniform base + lane*16)
__device__ __forceinline__ void gl_lds16(const u16* g, u16* l) {
  __builtin_amdgcn_global_load_lds((const __attribute__((address_space(1))) unsigned int*)g,
                                   (__attribute__((address_space(3))) unsigned int*)l, 16, 0, 0);
}

// counted waits + barrier fences (T4: never drain vmcnt to 0 in steady state)
#define WAITV4()  asm volatile("s_waitcnt vmcnt(4)" ::: "memory")
#define WAITV0()  asm volatile("s_waitcnt vmcnt(0)" ::: "memory")
#define PHASE_BAR() do { __builtin_amdgcn_sched_barrier(0); \
                         __builtin_amdgcn_s_barrier();      \
                         __builtin_amdgcn_sched_barrier(0); } while (0)

// k-permutation for V^T storage: kk = 16m + 4g + r -> s' = 32(m&1) + 8g + 4(m>>1) + r
__device__ __forceinline__ int kperm(int kk) {
  return ((kk & 0x10) << 1) | ((kk & 0x0C) << 1) | ((kk & 0x20) >> 3) | (kk & 3);
}

// ---------------- fp32 -> bf16 convert (float4 vectorized) ----------------
__global__ void cvt_kernel(const float* __restrict__ in, u16* __restrict__ out, int n4) {
  int i = blockIdx.x * blockDim.x + threadIdx.x;
  if (i >= n4) return;
  float4 v = reinterpret_cast<const float4*>(in)[i];
  ushort4 o;
  o.x = f2bf(v.x); o.y = f2bf(v.y); o.z = f2bf(v.z); o.w = f2bf(v.w);
  reinterpret_cast<ushort4*>(out)[i] = o;
}

// ---------------- transpose + convert: fp32 [R][C] -> bf16 [C][R] ----------------
__global__ void transpose_cvt(const float* __restrict__ in, u16* __restrict__ out, int R, int C) {
  __shared__ float tile[32][33];
  int c0 = blockIdx.x * 32, r0 = blockIdx.y * 32;
  for (int i = threadIdx.y; i < 32; i += 8)
    tile[i][threadIdx.x] = in[(size_t)(r0 + i) * C + c0 + threadIdx.x];
  __syncthreads();
  for (int i = threadIdx.y; i < 32; i += 8)
    out[(size_t)(c0 + i) * R + r0 + threadIdx.x] = f2bf(tile[threadIdx.x][i]);
}

// ---------------- bf16 GEMM: C[M,N] = A[M,K] * Bt[N,K]^T  (+bias) ----------------
// Ring-3 LDS, stage t+2 while computing t, counted vmcnt(4) at iter end (loads get a
// full iteration to land). XOR-swizzled LDS; XCD-bijective block swizzle.
// EPI 0: QKV epilogue; EPI 1: proj -> fp32 Out
template<int EPI>
__global__ __launch_bounds__(256)
void gemm_bt(const u16* __restrict__ A, const u16* __restrict__ Bt,
             const float* __restrict__ bias,
             u16* __restrict__ Qb, u16* __restrict__ Kb, u16* __restrict__ Vt,
             float* __restrict__ Out, int Kdim) {
  __shared__ __align__(16) u16 As[3][128 * 32];
  __shared__ __align__(16) u16 Bs[3][128 * 32];
  int tid = threadIdx.x;
  int lane = tid & 63, wid = tid >> 6;
  int wr = wid >> 1, wc = wid & 1;       // 2x2 waves; each computes 64x64
  constexpr int NX = (EPI == 0) ? 24 : 8;        // N tiles
  constexpr int NWG = NX * 64;                   // both % 8 == 0
  int orig = (int)blockIdx.x + NX * (int)blockIdx.y;
  int swz = (orig & 7) * (NWG >> 3) + (orig >> 3);
  int m0 = (swz / NX) * 128, n0 = (swz % NX) * 128;
  int l15 = lane & 15, g = lane >> 4;
  f32x4 acc[4][4] = {};
  int srow = tid >> 2;
  // pre-swizzled source chunk: LDS slot (row, c') holds global chunk c' ^ ((row>>1)&3)
  int scol = (((tid & 3) ^ ((tid >> 3) & 3)) * 8);
  // read-side chunk for frag row (base16 + l15): g ^ ((l15>>1)&3)
  int crd = (g ^ ((l15 >> 1) & 3)) * 8;

  const u16* a0p = &A[(size_t)(m0 + srow) * Kdim + scol];
  const u16* a1p = &A[(size_t)(m0 + 64 + srow) * Kdim + scol];
  const u16* b0p = &Bt[(size_t)(n0 + srow) * Kdim + scol];
  const u16* b1p = &Bt[(size_t)(n0 + 64 + srow) * Kdim + scol];

  // prologue: stage k-step 0 -> buf0, k-step 1 -> buf1
  gl_lds16(a0p,      &As[0][wid * 512]);
  gl_lds16(a1p,      &As[0][2048 + wid * 512]);
  gl_lds16(b0p,      &Bs[0][wid * 512]);
  gl_lds16(b1p,      &Bs[0][2048 + wid * 512]);
  gl_lds16(a0p + 32, &As[1][wid * 512]);
  gl_lds16(a1p + 32, &As[1][2048 + wid * 512]);
  gl_lds16(b0p + 32, &Bs[1][wid * 512]);
  gl_lds16(b1p + 32, &Bs[1][2048 + wid * 512]);
  WAITV4();            // k-step 0 landed; k-step 1 may fly
  PHASE_BAR();

  int nk = Kdim >> 5;
  int cur = 0;
  for (int t = 0; t < nk; ++t) {
    bool more = (t + 2) < nk;
    if (more) {   // stage k-step t+2 into buf (cur+2)%3 (region last read at t-1)
      int nxt = cur + 2; if (nxt >= 3) nxt -= 3;
      int ko = (t + 2) << 5;
      gl_lds16(a0p + ko, &As[nxt][wid * 512]);
      gl_lds16(a1p + ko, &As[nxt][2048 + wid * 512]);
      gl_lds16(b0p + ko, &Bs[nxt][wid * 512]);
      gl_lds16(b1p + ko, &Bs[nxt][2048 + wid * 512]);
    }
    short8 af[4], bfr[4];
#pragma unroll
    for (int m = 0; m < 4; ++m)
      af[m] = *reinterpret_cast<const short8*>(&As[cur][(wr * 64 + m * 16 + l15) * 32 + crd]);
#pragma unroll
    for (int n = 0; n < 4; ++n)
      bfr[n] = *reinterpret_cast<const short8*>(&Bs[cur][(wc * 64 + n * 16 + l15) * 32 + crd]);
    __builtin_amdgcn_s_setprio(1);
#pragma unroll
    for (int m = 0; m < 4; ++m)
#pragma unroll
      for (int n = 0; n < 4; ++n)
        acc[m][n] = __builtin_amdgcn_mfma_f32_16x16x32_bf16(af[m], bfr[n], acc[m][n], 0, 0, 0);
    __builtin_amdgcn_s_setprio(0);
    if (more) WAITV4();   // k-step t+1 (oldest 4 in flight) landed; t+2 still flying
    else      WAITV0();   // tail: everything landed
    PHASE_BAR();
    cur = cur + 1; if (cur >= 3) cur -= 3;
  }

  int bb = (m0 + wr * 64) >> 11;        // batch (wave-uniform; 64-row span never crosses)
  int sb = (m0 + wr * 64) & 2047;       // seq base (64-aligned)

  if (EPI == 1) {
#pragma unroll
    for (int m = 0; m < 4; ++m)
#pragma unroll
      for (int n = 0; n < 4; ++n) {
        int gcol = n0 + wc * 64 + n * 16 + l15;
        float bv = bias[gcol];
#pragma unroll
        for (int r = 0; r < 4; ++r) {
          int grow = m0 + wr * 64 + m * 16 + g * 4 + r;
          Out[(size_t)grow * 1024 + gcol] = acc[m][n][r] + bv;
        }
      }
  } else if (n0 < 1024) {               // Q block (scaled)
#pragma unroll
    for (int n = 0; n < 4; ++n) {
      int col = n0 + wc * 64 + n * 16 + l15;
      int hh = col >> 6, d = col & 63;
      float bv = bias[col];
      u16* qb = &Qb[(((size_t)(bb * 16 + hh) * 2048 + sb) << 6) + d];
#pragma unroll
      for (int m = 0; m < 4; ++m)
#pragma unroll
        for (int r = 0; r < 4; ++r)
          qb[(size_t)(m * 16 + g * 4 + r) << 6] = f2bf((acc[m][n][r] + bv) * QSCALE);
    }
  } else if (n0 < 2048) {               // K block
#pragma unroll
    for (int n = 0; n < 4; ++n) {
      int col = n0 - 1024 + wc * 64 + n * 16 + l15;
      int hh = col >> 6, d = col & 63;
      float bv = bias[1024 + col];
      u16* kb = &Kb[(((size_t)(bb * 16 + hh) * 2048 + sb) << 6) + d];
#pragma unroll
      for (int m = 0; m < 4; ++m)
#pragma unroll
        for (int r = 0; r < 4; ++r)
          kb[(size_t)(m * 16 + g * 4 + r) << 6] = f2bf(acc[m][n][r] + bv);
    }
  } else {                              // V block: vectorized k-permuted transpose write
#pragma unroll
    for (int n = 0; n < 4; ++n) {
      int cc = n0 - 2048 + wc * 64 + n * 16 + l15;
      int hh = cc >> 6, d = cc & 63;
      float bv = bias[2048 + cc];
      u16* dst = &Vt[((size_t)(bb * 16 + hh) * 64 + d) * 2048 + sb];
      u32x4 lo, hi;
      lo[0] = pk2(acc[0][n][0] + bv, acc[0][n][1] + bv);
      lo[1] = pk2(acc[0][n][2] + bv, acc[0][n][3] + bv);
      lo[2] = pk2(acc[2][n][0] + bv, acc[2][n][1] + bv);
      lo[3] = pk2(acc[2][n][2] + bv, acc[2][n][3] + bv);
      hi[0] = pk2(acc[1][n][0] + bv, acc[1][n][1] + bv);
      hi[1] = pk2(acc[1][n][2] + bv, acc[1][n][3] + bv);
      hi[2] = pk2(acc[3][n][0] + bv, acc[3][n][1] + bv);
      hi[3] = pk2(acc[3][n][2] + bv, acc[3][n][3] + bv);
      *reinterpret_cast<u32x4*>(dst + g * 8) = lo;
      *reinterpret_cast<u32x4*>(dst + 32 + g * 8) = hi;
    }
  }
}

// ---------------- flash attention (causal), swapped-QK^T, ring-3 LDS K/V ----------------
// grid: (16 tile-pairs, B*H). Block processes q-tile pair (31-bx, bx): uniform 33 iters.
// Stage it+2 while computing it; counted vmcnt(4) at iter end. Row-sum via ones-MFMA.
__global__ __launch_bounds__(256, 2)
void attn_kernel(const u16* __restrict__ Qb, const u16* __restrict__ Kb,
                 const u16* __restrict__ Vt, u16* __restrict__ Ctx) {
  __shared__ __align__(16) u16 lds[3][2][8][512];   // [ring][K|V][slot][1KB]
  int tid = threadIdx.x, lane = tid & 63, w = tid >> 6;
  int l15 = lane & 15, g = lane >> 4;
  int bh = blockIdx.y;
  const u16* Qh = Qb + (size_t)bh * Sq * HDq;
  const u16* Kh = Kb + (size_t)bh * Sq * HDq;
  const u16* Vh = Vt + (size_t)bh * HDq * Sq;
  int b = bh >> 4, h = bh & 15;

  int tileA = 31 - (int)blockIdx.x, tileB = (int)blockIdx.x;
  int nkA = tileA + 1;
  int ntot = nkA + tileB + 1;   // == 33 for every block

  const u16* ksrc = Kh + (size_t)(16 * w + l15) * 64 + 8 * g;
  const u16* vsrc = Vh + (size_t)(16 * w + l15) * Sq + 8 * g;

  int tile = tileA;
  int qbase = tileA * 64 + w * 16;

  short8 qf[2];
  qf[0] = *reinterpret_cast<const short8*>(&Qh[(size_t)(qbase + l15) * 64 + 8 * g]);
  qf[1] = *reinterpret_cast<const short8*>(&Qh[(size_t)(qbase + l15) * 64 + 32 + 8 * g]);

  // ones B-frag: output col 0 of PV-ones = row sum of P
  u16 onebits = (l15 == 0) ? (u16)0x3F80 : (u16)0;
  short8 vones;
#pragma unroll
  for (int i = 0; i < 8; ++i) vones[i] = (short)onebits;

  f32x4 acc[4] = {};
  f32x4 acc_l = {};
  float m_r = -INFINITY;

  // prologue: stage it=0 -> buf0, it=1 -> buf1 (it=1 may be tile B's kb=0)
  {
    gl_lds16(ksrc,      &lds[0][0][2 * w][0]);
    gl_lds16(ksrc + 32, &lds[0][0][2 * w + 1][0]);
    gl_lds16(vsrc,      &lds[0][1][2 * w][0]);
    gl_lds16(vsrc + 32, &lds[0][1][2 * w + 1][0]);
    int kb1 = (1 < nkA) ? 1 : 0;
    const u16* k1 = ksrc + ((size_t)kb1 << 12);
    const u16* v1 = vsrc + (kb1 << 6);
    gl_lds16(k1,      &lds[1][0][2 * w][0]);
    gl_lds16(k1 + 32, &lds[1][0][2 * w + 1][0]);
    gl_lds16(v1,      &lds[1][1][2 * w][0]);
    gl_lds16(v1 + 32, &lds[1][1][2 * w + 1][0]);
  }
  WAITV4();
  PHASE_BAR();

  int cur = 0;
  int kb = 0;

#pragma unroll 1
  for (int it = 0; it < ntot; ++it) {
    bool lastA = (it == nkA - 1);
    int k0 = kb << 6;
    int pf = it + 2;
    bool more = pf < ntot;

    if (more) {   // stage it+2 into ring slot (cur+2)%3
      int kb2 = pf < nkA ? pf : pf - nkA;
      int nxt = cur + 2; if (nxt >= 3) nxt -= 3;
      const u16* kp2 = ksrc + ((size_t)kb2 << 12);
      const u16* vp2 = vsrc + (kb2 << 6);
      gl_lds16(kp2,      &lds[nxt][0][2 * w][0]);
      gl_lds16(kp2 + 32, &lds[nxt][0][2 * w + 1][0]);
      gl_lds16(vp2,      &lds[nxt][1][2 * w][0]);
      gl_lds16(vp2 + 32, &lds[nxt][1][2 * w + 1][0]);
    }

    short8 kf[4][2], vbf[4][2];
#pragma unroll
    for (int j = 0; j < 4; ++j) {
      kf[j][0] = *reinterpret_cast<const short8*>(&lds[cur][0][2 * j][lane * 8]);
      kf[j][1] = *reinterpret_cast<const short8*>(&lds[cur][0][2 * j + 1][lane * 8]);
    }
#pragma unroll
    for (int n = 0; n < 4; ++n) {
      vbf[n][0] = *reinterpret_cast<const short8*>(&lds[cur][1][2 * n][lane * 8]);
      vbf[n][1] = *reinterpret_cast<const short8*>(&lds[cur][1][2 * n + 1][lane * 8]);
    }

    f32x4 sj[4];
    __builtin_amdgcn_s_setprio(1);
#pragma unroll
    for (int j = 0; j < 4; ++j) {
      f32x4 z = {};
      z = __builtin_amdgcn_mfma_f32_16x16x32_bf16(kf[j][0], qf[0], z, 0, 0, 0);
      z = __builtin_amdgcn_mfma_f32_16x16x32_bf16(kf[j][1], qf[1], z, 0, 0, 0);
      sj[j] = z;
    }
    __builtin_amdgcn_s_setprio(0);

    if (kb == tile) {   // diagonal block: causal mask
      int q = qbase + l15;
#pragma unroll
      for (int j = 0; j < 4; ++j)
#pragma unroll
        for (int r = 0; r < 4; ++r)
          if (k0 + 16 * j + 4 * g + r > q) sj[j][r] = -1e30f;
    }

    // row max (max3-fusable tree), then cross-g combine
    float a0 = fmaxf(fmaxf(sj[0][0], sj[0][1]), sj[0][2]);
    float a1 = fmaxf(fmaxf(sj[0][3], sj[1][0]), sj[1][1]);
    float a2 = fmaxf(fmaxf(sj[1][2], sj[1][3]), sj[2][0]);
    float a3 = fmaxf(fmaxf(sj[2][1], sj[2][2]), sj[2][3]);
    float a4 = fmaxf(fmaxf(sj[3][0], sj[3][1]), sj[3][2]);
    float mx = fmaxf(fmaxf(fmaxf(a0, a1), a2), fmaxf(fmaxf(a3, a4), sj[3][3]));
    mx = fmaxf(mx, __shfl_xor(mx, 16));
    mx = fmaxf(mx, __shfl_xor(mx, 32));

    float mn = m_r;
    if (!__all(mx - mn <= 8.0f)) {   // defer-max: rescale only on real growth
      float mnew = fmaxf(mn, mx);
      float scn = exp2f(mn - mnew);
      float scr[4];
#pragma unroll
      for (int r = 0; r < 4; ++r) scr[r] = __shfl(scn, 4 * g + r);
#pragma unroll
      for (int n = 0; n < 4; ++n)
#pragma unroll
        for (int r = 0; r < 4; ++r) acc[n][r] *= scr[r];
#pragma unroll
      for (int r = 0; r < 4; ++r) acc_l[r] *= scr[r];
      m_r = mnew;
      mn = mnew;
    }

    float p[4][4];
#pragma unroll
    for (int j = 0; j < 4; ++j)
#pragma unroll
      for (int r = 0; r < 4; ++r)
        p[j][r] = exp2f(sj[j][r] - mn);

    // pack P -> PV A-frags via v_cvt_pk_bf16_f32 (k' order matches perm'd Vt)
    u32x4 w0, w1;
    w0[0] = cvtpk(p[0][0], p[0][1]); w0[1] = cvtpk(p[0][2], p[0][3]);
    w0[2] = cvtpk(p[2][0], p[2][1]); w0[3] = cvtpk(p[2][2], p[2][3]);
    w1[0] = cvtpk(p[1][0], p[1][1]); w1[1] = cvtpk(p[1][2], p[1][3]);
    w1[2] = cvtpk(p[3][0], p[3][1]); w1[3] = cvtpk(p[3][2], p[3][3]);
    short8 pa0 = __builtin_bit_cast(short8, w0);
    short8 pa1 = __builtin_bit_cast(short8, w1);
    __builtin_amdgcn_s_setprio(1);
#pragma unroll
    for (int n = 0; n < 4; ++n) {
      acc[n] = __builtin_amdgcn_mfma_f32_16x16x32_bf16(pa0, vbf[n][0], acc[n], 0, 0, 0);
      acc[n] = __builtin_amdgcn_mfma_f32_16x16x32_bf16(pa1, vbf[n][1], acc[n], 0, 0, 0);
    }
    acc_l = __builtin_amdgcn_mfma_f32_16x16x32_bf16(pa0, vones, acc_l, 0, 0, 0);
    acc_l = __builtin_amdgcn_mfma_f32_16x16x32_bf16(pa1, vones, acc_l, 0, 0, 0);
    __builtin_amdgcn_s_setprio(0);

    kb++;
    if (lastA) {   // tile A done: write out, reset state, switch to tile B
      float lf[4];
#pragma unroll
      for (int r = 0; r < 4; ++r) lf[r] = __shfl(acc_l[r], 16 * g);
#pragma unroll
      for (int r = 0; r < 4; ++r) {
        float inv = 1.0f / lf[r];
        int row = qbase + 4 * g + r;
        size_t obase = ((size_t)(b * Sq + row)) * Dq + h * 64;
#pragma unroll
        for (int n = 0; n < 4; ++n)
          Ctx[obase + 16 * n + l15] = f2bf(acc[n][r] * inv);
      }
      qbase = tileB * 64 + w * 16;
      tile = tileB;
      kb = 0;
      qf[0] = *reinterpret_cast<const short8*>(&Qh[(size_t)(qbase + l15) * 64 + 8 * g]);
      qf[1] = *reinterpret_cast<const short8*>(&Qh[(size_t)(qbase + l15) * 64 + 32 + 8 * g]);
#pragma unroll
      for (int n = 0; n < 4; ++n) acc[n] = f32x4{};
      acc_l = f32x4{};
      m_r = -INFINITY;
    }

    if (more) WAITV4();   // it+1's stage (oldest in flight) landed; it+2 still flying
    else      WAITV0();
    PHASE_BAR();
    cur = cur + 1; if (cur >= 3) cur -= 3;
  }

  {   // tile B epilogue
    float lf[4];
#pragma unroll
    for (int r = 0; r < 4; ++r) lf[r] = __shfl(acc_l[r], 16 * g);
#pragma unroll
    for (int r = 0; r < 4; ++r) {
      float inv = 1.0f / lf[r];
      int row = qbase + 4 * g + r;
      size_t obase = ((size_t)(b * Sq + row)) * Dq + h * 64;
#pragma unroll
      for (int n = 0; n < 4; ++n)
        Ctx[obase + 16 * n + l15] = f2bf(acc[n][r] * inv);
    }
  }
}

extern "C" void kernel_launch(void* const* d_in, const int* in_sizes, int n_in,
                              void* d_out, int out_size, void* d_ws, size_t ws_size,
                              hipStream_t stream) {
  const float* X  = (const float*)d_in[0];   // [B,S,D] fp32
  const float* Wa = (const float*)d_in[1];   // [D,3D]
  const float* Ba = (const float*)d_in[2];   // [3D]
  const float* Wp = (const float*)d_in[3];   // [D,D]
  const float* Bp = (const float*)d_in[4];   // [D]
  float* Out = (float*)d_out;                // [B,S,D] fp32

  u16* ws  = (u16*)d_ws;
  u16* Xb  = ws;                                 // 8192*1024
  u16* WaT = Xb  + (size_t)BSq * Dq;             // 3072*1024
  u16* WpT = WaT + (size_t)3 * Dq * Dq;          // 1024*1024
  u16* Qb  = WpT + (size_t)Dq * Dq;              // 64*2048*64
  u16* Kb  = Qb  + (size_t)Bq * Hq * Sq * HDq;
  u16* Vt  = Kb  + (size_t)Bq * Hq * Sq * HDq;
  u16* Ctx = Vt  + (size_t)Bq * Hq * Sq * HDq;   // 8192*1024

  // 1) convert X to bf16
  cvt_kernel<<<(BSq * Dq / 4 + 255) / 256, 256, 0, stream>>>(X, Xb, BSq * Dq / 4);
  // 2) transpose+convert weights: W[K][N] -> WT[N][K] bf16
  transpose_cvt<<<dim3(3 * Dq / 32, Dq / 32), dim3(32, 8), 0, stream>>>(Wa, WaT, Dq, 3 * Dq);
  transpose_cvt<<<dim3(Dq / 32, Dq / 32), dim3(32, 8), 0, stream>>>(Wp, WpT, Dq, Dq);
  // 3) QKV GEMM (M=8192, N=3072, K=1024) with Q/K/V scatter epilogue
  gemm_bt<0><<<dim3(3 * Dq / 128, BSq / 128), 256, 0, stream>>>(Xb, WaT, Ba, Qb, Kb, Vt, nullptr, Dq);
  // 4) causal flash attention -> Ctx [B,S,H*HD] bf16 (paired equal-work blocks)
  attn_kernel<<<dim3(16, Bq * Hq), 256, 0, stream>>>(Qb, Kb, Vt, Ctx);
  // 5) output projection (M=8192, N=1024, K=1024) -> fp32 out
  gemm_bt<1><<<dim3(Dq / 128, BSq / 128), 256, 0, stream>>>(Ctx, WpT, Bp, nullptr, nullptr, nullptr, Out, Dq);
}

// Round 10
// 196.945 us; speedup vs baseline: 1.1522x; 1.1522x over previous
//
#include <hip/hip_runtime.h>

typedef unsigned short u16;
typedef __attribute__((ext_vector_type(8))) short short8;
typedef __attribute__((ext_vector_type(4))) float f32x4;
typedef __attribute__((ext_vector_type(4))) unsigned u32x4;

// Problem dims
#define Bq 4
#define Sq 2048
#define Dq 1024
#define Hq 16
#define HDq 64
#define BSq 8192   // B*S

// Q pre-scale: 1/sqrt(64) * log2(e)  (softmax done in exp2 domain)
#define QSCALE 0.18033688011112042f

__device__ __forceinline__ u16 f2bf(float f) {
  unsigned u = __builtin_bit_cast(unsigned, f);
  unsigned r = u + 0x7fffu + ((u >> 16) & 1u);
  return (u16)(r >> 16);
}

// pack two floats -> (bf16(a) | bf16(b)<<16)
__device__ __forceinline__ unsigned pk2(float a, float b) {
  unsigned ua = __builtin_bit_cast(unsigned, a) + 0x8000u;
  unsigned ub = __builtin_bit_cast(unsigned, b) + 0x8000u;
  return __builtin_amdgcn_perm(ub, ua, 0x07060302u);
}

// single-instruction pack: dst = {lo: bf16(a), hi: bf16(b)}
__device__ __forceinline__ unsigned cvtpk(float a, float b) {
  unsigned r;
  asm("v_cvt_pk_bf16_f32 %0, %1, %2" : "=v"(r) : "v"(a), "v"(b));
  return r;
}

// async global->LDS, 16B per lane (dest = wave-uniform base + lane*16)
__device__ __forceinline__ void gl_lds16(const u16* g, u16* l) {
  __builtin_amdgcn_global_load_lds((const __attribute__((address_space(1))) unsigned int*)g,
                                   (__attribute__((address_space(3))) unsigned int*)l, 16, 0, 0);
}

// counted waits + barrier fences (GEMM only; attn uses plain __syncthreads)
#define WAITV4()  asm volatile("s_waitcnt vmcnt(4)" ::: "memory")
#define WAITV0()  asm volatile("s_waitcnt vmcnt(0)" ::: "memory")
#define PHASE_BAR() do { __builtin_amdgcn_sched_barrier(0); \
                         __builtin_amdgcn_s_barrier();      \
                         __builtin_amdgcn_sched_barrier(0); } while (0)

// k-permutation for V^T storage: kk = 16m + 4g + r -> s' = 32(m&1) + 8g + 4(m>>1) + r
__device__ __forceinline__ int kperm(int kk) {
  return ((kk & 0x10) << 1) | ((kk & 0x0C) << 1) | ((kk & 0x20) >> 3) | (kk & 3);
}

// ---------------- fp32 -> bf16 convert (float4 vectorized) ----------------
__global__ void cvt_kernel(const float* __restrict__ in, u16* __restrict__ out, int n4) {
  int i = blockIdx.x * blockDim.x + threadIdx.x;
  if (i >= n4) return;
  float4 v = reinterpret_cast<const float4*>(in)[i];
  ushort4 o;
  o.x = f2bf(v.x); o.y = f2bf(v.y); o.z = f2bf(v.z); o.w = f2bf(v.w);
  reinterpret_cast<ushort4*>(out)[i] = o;
}

// ---------------- transpose + convert: fp32 [R][C] -> bf16 [C][R] ----------------
__global__ void transpose_cvt(const float* __restrict__ in, u16* __restrict__ out, int R, int C) {
  __shared__ float tile[32][33];
  int c0 = blockIdx.x * 32, r0 = blockIdx.y * 32;
  for (int i = threadIdx.y; i < 32; i += 8)
    tile[i][threadIdx.x] = in[(size_t)(r0 + i) * C + c0 + threadIdx.x];
  __syncthreads();
  for (int i = threadIdx.y; i < 32; i += 8)
    out[(size_t)(c0 + i) * R + r0 + threadIdx.x] = f2bf(tile[threadIdx.x][i]);
}

// ---------------- bf16 GEMM: C[M,N] = A[M,K] * Bt[N,K]^T  (+bias) ----------------
// Ring-3 LDS, stage t+2 while computing t, counted vmcnt(4) at iter end.
// XOR-swizzled LDS; XCD-bijective block swizzle.
// EPI 0: QKV epilogue; EPI 1: proj -> fp32 Out
template<int EPI>
__global__ __launch_bounds__(256)
void gemm_bt(const u16* __restrict__ A, const u16* __restrict__ Bt,
             const float* __restrict__ bias,
             u16* __restrict__ Qb, u16* __restrict__ Kb, u16* __restrict__ Vt,
             float* __restrict__ Out, int Kdim) {
  __shared__ __align__(16) u16 As[3][128 * 32];
  __shared__ __align__(16) u16 Bs[3][128 * 32];
  int tid = threadIdx.x;
  int lane = tid & 63, wid = tid >> 6;
  int wr = wid >> 1, wc = wid & 1;       // 2x2 waves; each computes 64x64
  constexpr int NX = (EPI == 0) ? 24 : 8;        // N tiles
  constexpr int NWG = NX * 64;                   // both % 8 == 0
  int orig = (int)blockIdx.x + NX * (int)blockIdx.y;
  int swz = (orig & 7) * (NWG >> 3) + (orig >> 3);
  int m0 = (swz / NX) * 128, n0 = (swz % NX) * 128;
  int l15 = lane & 15, g = lane >> 4;
  f32x4 acc[4][4] = {};
  int srow = tid >> 2;
  // pre-swizzled source chunk: LDS slot (row, c') holds global chunk c' ^ ((row>>1)&3)
  int scol = (((tid & 3) ^ ((tid >> 3) & 3)) * 8);
  // read-side chunk for frag row (base16 + l15): g ^ ((l15>>1)&3)
  int crd = (g ^ ((l15 >> 1) & 3)) * 8;

  const u16* a0p = &A[(size_t)(m0 + srow) * Kdim + scol];
  const u16* a1p = &A[(size_t)(m0 + 64 + srow) * Kdim + scol];
  const u16* b0p = &Bt[(size_t)(n0 + srow) * Kdim + scol];
  const u16* b1p = &Bt[(size_t)(n0 + 64 + srow) * Kdim + scol];

  // prologue: stage k-step 0 -> buf0, k-step 1 -> buf1
  gl_lds16(a0p,      &As[0][wid * 512]);
  gl_lds16(a1p,      &As[0][2048 + wid * 512]);
  gl_lds16(b0p,      &Bs[0][wid * 512]);
  gl_lds16(b1p,      &Bs[0][2048 + wid * 512]);
  gl_lds16(a0p + 32, &As[1][wid * 512]);
  gl_lds16(a1p + 32, &As[1][2048 + wid * 512]);
  gl_lds16(b0p + 32, &Bs[1][wid * 512]);
  gl_lds16(b1p + 32, &Bs[1][2048 + wid * 512]);
  WAITV4();            // k-step 0 landed; k-step 1 may fly
  PHASE_BAR();

  int nk = Kdim >> 5;
  int cur = 0;
  for (int t = 0; t < nk; ++t) {
    bool more = (t + 2) < nk;
    if (more) {   // stage k-step t+2 into buf (cur+2)%3 (region last read at t-1)
      int nxt = cur + 2; if (nxt >= 3) nxt -= 3;
      int ko = (t + 2) << 5;
      gl_lds16(a0p + ko, &As[nxt][wid * 512]);
      gl_lds16(a1p + ko, &As[nxt][2048 + wid * 512]);
      gl_lds16(b0p + ko, &Bs[nxt][wid * 512]);
      gl_lds16(b1p + ko, &Bs[nxt][2048 + wid * 512]);
    }
    short8 af[4], bfr[4];
#pragma unroll
    for (int m = 0; m < 4; ++m)
      af[m] = *reinterpret_cast<const short8*>(&As[cur][(wr * 64 + m * 16 + l15) * 32 + crd]);
#pragma unroll
    for (int n = 0; n < 4; ++n)
      bfr[n] = *reinterpret_cast<const short8*>(&Bs[cur][(wc * 64 + n * 16 + l15) * 32 + crd]);
    __builtin_amdgcn_s_setprio(1);
#pragma unroll
    for (int m = 0; m < 4; ++m)
#pragma unroll
      for (int n = 0; n < 4; ++n)
        acc[m][n] = __builtin_amdgcn_mfma_f32_16x16x32_bf16(af[m], bfr[n], acc[m][n], 0, 0, 0);
    __builtin_amdgcn_s_setprio(0);
    if (more) WAITV4();   // k-step t+1 (oldest 4 in flight) landed; t+2 still flying
    else      WAITV0();   // tail: everything landed
    PHASE_BAR();
    cur = cur + 1; if (cur >= 3) cur -= 3;
  }

  int bb = (m0 + wr * 64) >> 11;        // batch (wave-uniform; 64-row span never crosses)
  int sb = (m0 + wr * 64) & 2047;       // seq base (64-aligned)

  if (EPI == 1) {
#pragma unroll
    for (int m = 0; m < 4; ++m)
#pragma unroll
      for (int n = 0; n < 4; ++n) {
        int gcol = n0 + wc * 64 + n * 16 + l15;
        float bv = bias[gcol];
#pragma unroll
        for (int r = 0; r < 4; ++r) {
          int grow = m0 + wr * 64 + m * 16 + g * 4 + r;
          Out[(size_t)grow * 1024 + gcol] = acc[m][n][r] + bv;
        }
      }
  } else if (n0 < 1024) {               // Q block (scaled)
#pragma unroll
    for (int n = 0; n < 4; ++n) {
      int col = n0 + wc * 64 + n * 16 + l15;
      int hh = col >> 6, d = col & 63;
      float bv = bias[col];
      u16* qb = &Qb[(((size_t)(bb * 16 + hh) * 2048 + sb) << 6) + d];
#pragma unroll
      for (int m = 0; m < 4; ++m)
#pragma unroll
        for (int r = 0; r < 4; ++r)
          qb[(size_t)(m * 16 + g * 4 + r) << 6] = f2bf((acc[m][n][r] + bv) * QSCALE);
    }
  } else if (n0 < 2048) {               // K block
#pragma unroll
    for (int n = 0; n < 4; ++n) {
      int col = n0 - 1024 + wc * 64 + n * 16 + l15;
      int hh = col >> 6, d = col & 63;
      float bv = bias[1024 + col];
      u16* kb = &Kb[(((size_t)(bb * 16 + hh) * 2048 + sb) << 6) + d];
#pragma unroll
      for (int m = 0; m < 4; ++m)
#pragma unroll
        for (int r = 0; r < 4; ++r)
          kb[(size_t)(m * 16 + g * 4 + r) << 6] = f2bf(acc[m][n][r] + bv);
    }
  } else {                              // V block: vectorized k-permuted transpose write
#pragma unroll
    for (int n = 0; n < 4; ++n) {
      int cc = n0 - 2048 + wc * 64 + n * 16 + l15;
      int hh = cc >> 6, d = cc & 63;
      float bv = bias[2048 + cc];
      u16* dst = &Vt[((size_t)(bb * 16 + hh) * 64 + d) * 2048 + sb];
      u32x4 lo, hi;
      lo[0] = pk2(acc[0][n][0] + bv, acc[0][n][1] + bv);
      lo[1] = pk2(acc[0][n][2] + bv, acc[0][n][3] + bv);
      lo[2] = pk2(acc[2][n][0] + bv, acc[2][n][1] + bv);
      lo[3] = pk2(acc[2][n][2] + bv, acc[2][n][3] + bv);
      hi[0] = pk2(acc[1][n][0] + bv, acc[1][n][1] + bv);
      hi[1] = pk2(acc[1][n][2] + bv, acc[1][n][3] + bv);
      hi[2] = pk2(acc[3][n][0] + bv, acc[3][n][1] + bv);
      hi[3] = pk2(acc[3][n][2] + bv, acc[3][n][3] + bv);
      *reinterpret_cast<u32x4*>(dst + g * 8) = lo;
      *reinterpret_cast<u32x4*>(dst + 32 + g * 8) = hi;
    }
  }
}

// ---------------- flash attention (causal), swapped-QK^T, LDS-staged K/V ----------------
// grid: (16 tile-pairs, B*H). Block processes q-tile pair (31-bx, bx): uniform 33 iters.
// dbuf-2 LDS (32KB), prefetch next during compute, one __syncthreads per iter.
// Row-sum via constant ones B-frag on the MFMA pipe (no VALU reduce).
__global__ __launch_bounds__(256, 2)
void attn_kernel(const u16* __restrict__ Qb, const u16* __restrict__ Kb,
                 const u16* __restrict__ Vt, u16* __restrict__ Ctx) {
  __shared__ __align__(16) u16 lds[2][2][8][512];   // [dbuf][K|V][slot][1KB]
  int tid = threadIdx.x, lane = tid & 63, w = tid >> 6;
  int l15 = lane & 15, g = lane >> 4;
  int bh = blockIdx.y;
  const u16* Qh = Qb + (size_t)bh * Sq * HDq;
  const u16* Kh = Kb + (size_t)bh * Sq * HDq;
  const u16* Vh = Vt + (size_t)bh * HDq * Sq;
  int b = bh >> 4, h = bh & 15;

  int tileA = 31 - (int)blockIdx.x, tileB = (int)blockIdx.x;
  int nkA = tileA + 1;
  int ntot = nkA + tileB + 1;   // == 33 for every block

  const u16* ksrc = Kh + (size_t)(16 * w + l15) * 64 + 8 * g;
  const u16* vsrc = Vh + (size_t)(16 * w + l15) * Sq + 8 * g;
  const u16* kpre = ksrc + 4096;   // next prefetch source (kb=1)
  const u16* vpre = vsrc + 64;

  int tile = tileA;
  int qbase = tileA * 64 + w * 16;

  short8 qf[2];
  qf[0] = *reinterpret_cast<const short8*>(&Qh[(size_t)(qbase + l15) * 64 + 8 * g]);
  qf[1] = *reinterpret_cast<const short8*>(&Qh[(size_t)(qbase + l15) * 64 + 32 + 8 * g]);

  // ones B-frag: output col 0 of PV-ones = row sum of P
  u16 onebits = (l15 == 0) ? (u16)0x3F80 : (u16)0;
  short8 vones;
#pragma unroll
  for (int i = 0; i < 8; ++i) vones[i] = (short)onebits;

  f32x4 acc[4] = {};
  f32x4 acc_l = {};
  float m_r = -INFINITY;

  gl_lds16(ksrc,      &lds[0][0][2 * w][0]);
  gl_lds16(ksrc + 32, &lds[0][0][2 * w + 1][0]);
  gl_lds16(vsrc,      &lds[0][1][2 * w][0]);
  gl_lds16(vsrc + 32, &lds[0][1][2 * w + 1][0]);
  __syncthreads();
  int cur = 0;
  int kb = 0;

#pragma unroll 1
  for (int it = 0; it < ntot; ++it) {
    bool lastA = (it == nkA - 1);
    int k0 = kb << 6;

    if (it + 1 < ntot) {   // prefetch next iteration (strength-reduced pointers)
      gl_lds16(kpre,      &lds[cur ^ 1][0][2 * w][0]);
      gl_lds16(kpre + 32, &lds[cur ^ 1][0][2 * w + 1][0]);
      gl_lds16(vpre,      &lds[cur ^ 1][1][2 * w][0]);
      gl_lds16(vpre + 32, &lds[cur ^ 1][1][2 * w + 1][0]);
      if (it == nkA - 2) { kpre = ksrc; vpre = vsrc; }   // wrap to tile-B's kb=0
      else               { kpre += 4096; vpre += 64; }
    }

    short8 kf[4][2], vbf[4][2];
#pragma unroll
    for (int j = 0; j < 4; ++j) {
      kf[j][0] = *reinterpret_cast<const short8*>(&lds[cur][0][2 * j][lane * 8]);
      kf[j][1] = *reinterpret_cast<const short8*>(&lds[cur][0][2 * j + 1][lane * 8]);
    }
#pragma unroll
    for (int n = 0; n < 4; ++n) {
      vbf[n][0] = *reinterpret_cast<const short8*>(&lds[cur][1][2 * n][lane * 8]);
      vbf[n][1] = *reinterpret_cast<const short8*>(&lds[cur][1][2 * n + 1][lane * 8]);
    }

    f32x4 sj[4];
    __builtin_amdgcn_s_setprio(1);
#pragma unroll
    for (int j = 0; j < 4; ++j) {
      f32x4 z = {};
      z = __builtin_amdgcn_mfma_f32_16x16x32_bf16(kf[j][0], qf[0], z, 0, 0, 0);
      z = __builtin_amdgcn_mfma_f32_16x16x32_bf16(kf[j][1], qf[1], z, 0, 0, 0);
      sj[j] = z;
    }
    __builtin_amdgcn_s_setprio(0);

    if (kb == tile) {   // diagonal block: causal mask
      int q = qbase + l15;
#pragma unroll
      for (int j = 0; j < 4; ++j)
#pragma unroll
        for (int r = 0; r < 4; ++r)
          if (k0 + 16 * j + 4 * g + r > q) sj[j][r] = -1e30f;
    }

    // row max (max3-fusable tree), then cross-g combine
    float a0 = fmaxf(fmaxf(sj[0][0], sj[0][1]), sj[0][2]);
    float a1 = fmaxf(fmaxf(sj[0][3], sj[1][0]), sj[1][1]);
    float a2 = fmaxf(fmaxf(sj[1][2], sj[1][3]), sj[2][0]);
    float a3 = fmaxf(fmaxf(sj[2][1], sj[2][2]), sj[2][3]);
    float a4 = fmaxf(fmaxf(sj[3][0], sj[3][1]), sj[3][2]);
    float mx = fmaxf(fmaxf(fmaxf(a0, a1), a2), fmaxf(fmaxf(a3, a4), sj[3][3]));
    mx = fmaxf(mx, __shfl_xor(mx, 16));
    mx = fmaxf(mx, __shfl_xor(mx, 32));

    float mn = m_r;
    if (!__all(mx - mn <= 8.0f)) {   // defer-max: rescale only on real growth
      float mnew = fmaxf(mn, mx);
      float scn = exp2f(mn - mnew);
      float scr[4];
#pragma unroll
      for (int r = 0; r < 4; ++r) scr[r] = __shfl(scn, 4 * g + r);
#pragma unroll
      for (int n = 0; n < 4; ++n)
#pragma unroll
        for (int r = 0; r < 4; ++r) acc[n][r] *= scr[r];
#pragma unroll
      for (int r = 0; r < 4; ++r) acc_l[r] *= scr[r];
      m_r = mnew;
      mn = mnew;
    }

    float p[4][4];
#pragma unroll
    for (int j = 0; j < 4; ++j)
#pragma unroll
      for (int r = 0; r < 4; ++r)
        p[j][r] = exp2f(sj[j][r] - mn);

    // pack P -> PV A-frags via v_cvt_pk_bf16_f32 (k' order matches perm'd Vt)
    u32x4 w0, w1;
    w0[0] = cvtpk(p[0][0], p[0][1]); w0[1] = cvtpk(p[0][2], p[0][3]);
    w0[2] = cvtpk(p[2][0], p[2][1]); w0[3] = cvtpk(p[2][2], p[2][3]);
    w1[0] = cvtpk(p[1][0], p[1][1]); w1[1] = cvtpk(p[1][2], p[1][3]);
    w1[2] = cvtpk(p[3][0], p[3][1]); w1[3] = cvtpk(p[3][2], p[3][3]);
    short8 pa0 = __builtin_bit_cast(short8, w0);
    short8 pa1 = __builtin_bit_cast(short8, w1);
    __builtin_amdgcn_s_setprio(1);
#pragma unroll
    for (int n = 0; n < 4; ++n) {
      acc[n] = __builtin_amdgcn_mfma_f32_16x16x32_bf16(pa0, vbf[n][0], acc[n], 0, 0, 0);
      acc[n] = __builtin_amdgcn_mfma_f32_16x16x32_bf16(pa1, vbf[n][1], acc[n], 0, 0, 0);
    }
    acc_l = __builtin_amdgcn_mfma_f32_16x16x32_bf16(pa0, vones, acc_l, 0, 0, 0);
    acc_l = __builtin_amdgcn_mfma_f32_16x16x32_bf16(pa1, vones, acc_l, 0, 0, 0);
    __builtin_amdgcn_s_setprio(0);

    kb++;
    if (lastA) {   // tile A done: write out, reset state, switch to tile B
      float lf[4];
#pragma unroll
      for (int r = 0; r < 4; ++r) lf[r] = __shfl(acc_l[r], 16 * g);
#pragma unroll
      for (int r = 0; r < 4; ++r) {
        float inv = 1.0f / lf[r];
        int row = qbase + 4 * g + r;
        size_t obase = ((size_t)(b * Sq + row)) * Dq + h * 64;
#pragma unroll
        for (int n = 0; n < 4; ++n)
          Ctx[obase + 16 * n + l15] = f2bf(acc[n][r] * inv);
      }
      qbase = tileB * 64 + w * 16;
      tile = tileB;
      kb = 0;
      qf[0] = *reinterpret_cast<const short8*>(&Qh[(size_t)(qbase + l15) * 64 + 8 * g]);
      qf[1] = *reinterpret_cast<const short8*>(&Qh[(size_t)(qbase + l15) * 64 + 32 + 8 * g]);
#pragma unroll
      for (int n = 0; n < 4; ++n) acc[n] = f32x4{};
      acc_l = f32x4{};
      m_r = -INFINITY;
    }

    __syncthreads();
    cur ^= 1;
  }

  {   // tile B epilogue
    float lf[4];
#pragma unroll
    for (int r = 0; r < 4; ++r) lf[r] = __shfl(acc_l[r], 16 * g);
#pragma unroll
    for (int r = 0; r < 4; ++r) {
      float inv = 1.0f / lf[r];
      int row = qbase + 4 * g + r;
      size_t obase = ((size_t)(b * Sq + row)) * Dq + h * 64;
#pragma unroll
      for (int n = 0; n < 4; ++n)
        Ctx[obase + 16 * n + l15] = f2bf(acc[n][r] * inv);
    }
  }
}

extern "C" void kernel_launch(void* const* d_in, const int* in_sizes, int n_in,
                              void* d_out, int out_size, void* d_ws, size_t ws_size,
                              hipStream_t stream) {
  const float* X  = (const float*)d_in[0];   // [B,S,D] fp32
  const float* Wa = (const float*)d_in[1];   // [D,3D]
  const float* Ba = (const float*)d_in[2];   // [3D]
  const float* Wp = (const float*)d_in[3];   // [D,D]
  const float* Bp = (const float*)d_in[4];   // [D]
  float* Out = (float*)d_out;                // [B,S,D] fp32

  u16* ws  = (u16*)d_ws;
  u16* Xb  = ws;                                 // 8192*1024
  u16* WaT = Xb  + (size_t)BSq * Dq;             // 3072*1024
  u16* WpT = WaT + (size_t)3 * Dq * Dq;          // 1024*1024
  u16* Qb  = WpT + (size_t)Dq * Dq;              // 64*2048*64
  u16* Kb  = Qb  + (size_t)Bq * Hq * Sq * HDq;
  u16* Vt  = Kb  + (size_t)Bq * Hq * Sq * HDq;
  u16* Ctx = Vt  + (size_t)Bq * Hq * Sq * HDq;   // 8192*1024

  // 1) convert X to bf16
  cvt_kernel<<<(BSq * Dq / 4 + 255) / 256, 256, 0, stream>>>(X, Xb, BSq * Dq / 4);
  // 2) transpose+convert weights: W[K][N] -> WT[N][K] bf16
  transpose_cvt<<<dim3(3 * Dq / 32, Dq / 32), dim3(32, 8), 0, stream>>>(Wa, WaT, Dq, 3 * Dq);
  transpose_cvt<<<dim3(Dq / 32, Dq / 32), dim3(32, 8), 0, stream>>>(Wp, WpT, Dq, Dq);
  // 3) QKV GEMM (M=8192, N=3072, K=1024) with Q/K/V scatter epilogue
  gemm_bt<0><<<dim3(3 * Dq / 128, BSq / 128), 256, 0, stream>>>(Xb, WaT, Ba, Qb, Kb, Vt, nullptr, Dq);
  // 4) causal flash attention -> Ctx [B,S,H*HD] bf16 (paired equal-work blocks)
  attn_kernel<<<dim3(16, Bq * Hq), 256, 0, stream>>>(Qb, Kb, Vt, Ctx);
  // 5) output projection (M=8192, N=1024, K=1024) -> fp32 out
  gemm_bt<1><<<dim3(Dq / 128, BSq / 128), 256, 0, stream>>>(Ctx, WpT, Bp, nullptr, nullptr, nullptr, Out, Dq);
}